// Round 4
// baseline (204.282 us; speedup 1.0000x reference)
//
#include <hip/hip_runtime.h>
#include <cstdint>

#define S_LEN 2048
#define EMB   2048
#define NHEAD 32
#define NKV   8
#define HDIM  64
#define NQKV  3072   // (H+2G)*D

typedef __attribute__((ext_vector_type(8))) short bf16x8;
typedef __attribute__((ext_vector_type(4))) float f32x4;

#define GPTR const __attribute__((address_space(1))) void*
#define LPTR __attribute__((address_space(3))) void*

__device__ __forceinline__ unsigned short f2bf(float f){
  union { float f; unsigned int u; } v; v.f = f;
  unsigned int r = v.u + 0x7FFFu + ((v.u >> 16) & 1u);
  return (unsigned short)(r >> 16);
}
__device__ __forceinline__ float bf2f(unsigned short u){
  union { unsigned int u; float f; } v; v.u = ((unsigned int)u) << 16;
  return v.f;
}
__device__ __forceinline__ float yarn_eff(float ifr){
  const float freq = __expf(-ifr * (9.210340371976184f / 32.0f));  // 10000^(-2i/64)
  const float wl = 6.283185307179586f / freq;
  float t = fminf(fmaxf((wl - 128.0f) * (1.0f / 3968.0f), 0.f), 1.f);
  return freq * (1.0f - 0.5f * t) * 1.0693147180559945f;           // * conc
}

// ---------------- fp32 -> bf16 conversion (x, Wqkv; Wout is fused into attn) ----------------
__global__ __launch_bounds__(256) void cvt3_kernel(const float* __restrict__ a, unsigned short* __restrict__ da, int na,
                                                   const float* __restrict__ b, unsigned short* __restrict__ db, int nb,
                                                   const float* __restrict__ c, unsigned short* __restrict__ dc, int nc){
  int i = blockIdx.x * 256 + threadIdx.x;
  const float* s; unsigned short* d;
  if (i < na){ s = a; d = da; }
  else if (i < na + nb){ s = b; d = db; i -= na; }
  else if (i < na + nb + nc){ s = c; d = dc; i -= na + nb; }
  else return;
  const float4 v = ((const float4*)s)[i];
  ushort4 o;
  o.x = f2bf(v.x); o.y = f2bf(v.y); o.z = f2bf(v.z); o.w = f2bf(v.w);
  ((ushort4*)d)[i] = o;
}

// LDS granule swizzle (both GEMMs): row r's logical k-quad q (16B granule) stored at
// granule q ^ ((r>>1)&3). global_load_lds writes linearly -> swizzle applied by
// permuting the per-lane GLOBAL source column; un-applied on the ds_read side.
// Verified round 1: SQ_LDS_BANK_CONFLICT = 0.

// ---------------- bf16 MFMA GEMM, C = A * B^T + bias, TM x 128 tile (out-proj) ----------------
template<int OUT_BF16, int ROPE, int TM>
__global__ __launch_bounds__(256) void gemm_bt(const unsigned short* __restrict__ A,
                                               const unsigned short* __restrict__ B,
                                               const float* __restrict__ bias,
                                               void* __restrict__ Cout,
                                               const int* __restrict__ pos,
                                               int M, int N, int K){
  constexpr int MI = TM / 32;            // i-frags per wave (128->4, 64->2)
  constexpr int AI = TM / 64;            // A staging issues per wave per sub-tile
  __shared__ unsigned short As[4*TM*32];   // 2 epochs x 2 subs
  __shared__ unsigned short Bs[4*128*32];  // 32 KB
  const int tid  = threadIdx.x;
  const int lane = tid & 63;
  const int wid  = tid >> 6;
  const int m0 = blockIdx.y * TM;
  const int n0 = blockIdx.x * 128;
  const int wm = (wid >> 1) * (TM/2);
  const int wn = (wid & 1) * 64;
  const int fm = lane & 15;
  const int quad = lane >> 4;
  const int csw8 = (quad ^ ((fm >> 1) & 3)) * 8;   // swizzled read granule

  f32x4 acc[MI][4];
#pragma unroll
  for (int i = 0; i < MI; ++i)
#pragma unroll
    for (int j = 0; j < 4; ++j) acc[i][j] = {0.f, 0.f, 0.f, 0.f};

  const int srow = lane >> 2;                                    // 0..15
  const int scol = (((lane & 3) ^ ((lane >> 3) & 3)) * 8);       // swizzled source col
  const unsigned short* Ag = A + (size_t)(m0 + wid*(TM/4) + srow) * K + scol;
  const unsigned short* Bg = B + (size_t)(n0 + wid*32 + srow) * K + scol;
  unsigned short* AsW = &As[(wid*(TM/4))*32];
  unsigned short* BsW = &Bs[(wid*32)*32];

  auto stage_sub = [&](int k0, int slot){
    unsigned short* dA = AsW + slot*(TM*32);
    unsigned short* dB = BsW + slot*(128*32);
#pragma unroll
    for (int t = 0; t < AI; ++t)
      __builtin_amdgcn_global_load_lds((GPTR)(Ag + k0 + (size_t)(t*16)*K), (LPTR)(dA + t*16*32), 16, 0, 0);
    __builtin_amdgcn_global_load_lds((GPTR)(Bg + k0), (LPTR)dB, 16, 0, 0);
    __builtin_amdgcn_global_load_lds((GPTR)(Bg + k0 + (size_t)16*K), (LPTR)(dB + 16*32), 16, 0, 0);
  };

  stage_sub(0, 0);  stage_sub(32, 1);
  stage_sub(64, 2); stage_sub(96, 3);

  const int KEP = K >> 6;   // 64-wide epochs
  for (int e = 0; e < KEP; ++e){
    const int buf = e & 1;
    if (e + 1 < KEP){
      if constexpr (TM == 128) asm volatile("s_waitcnt vmcnt(8)" ::: "memory");
      else                     asm volatile("s_waitcnt vmcnt(6)" ::: "memory");
    } else {
      asm volatile("s_waitcnt vmcnt(0)" ::: "memory");
    }
    asm volatile("s_barrier" ::: "memory");

    bf16x8 af[2][MI], bfr[2][4];
#pragma unroll
    for (int s = 0; s < 2; ++s){
      const unsigned short* Ab = As + (buf*2+s)*(TM*32);
      const unsigned short* Bb = Bs + (buf*2+s)*(128*32);
#pragma unroll
      for (int i = 0; i < MI; ++i) af[s][i]  = *(const bf16x8*)&Ab[(wm + i*16 + fm)*32 + csw8];
#pragma unroll
      for (int j = 0; j < 4; ++j)  bfr[s][j] = *(const bf16x8*)&Bb[(wn + j*16 + fm)*32 + csw8];
    }
#pragma unroll
    for (int s = 0; s < 2; ++s)
#pragma unroll
      for (int i = 0; i < MI; ++i)
#pragma unroll
        for (int j = 0; j < 4; ++j)
          acc[i][j] = __builtin_amdgcn_mfma_f32_16x16x32_bf16(af[s][i], bfr[s][j], acc[i][j], 0, 0, 0);

    asm volatile("s_barrier" ::: "memory");
    if (e + 2 < KEP){
      stage_sub((e+2)*64,      buf*2);
      stage_sub((e+2)*64 + 32, buf*2 + 1);
    }
  }

  float bv[4];
#pragma unroll
  for (int j = 0; j < 4; ++j) bv[j] = bias[n0 + wn + j*16 + fm];

  const bool dorope = ROPE && (n0 + wn) < 2560;
  if (dorope){
    const float eff0 = yarn_eff((float)fm);
    const float eff1 = yarn_eff((float)(fm + 16));
#pragma unroll
    for (int i = 0; i < MI; ++i){
#pragma unroll
      for (int r = 0; r < 4; ++r){
        const int row = m0 + wm + i*16 + quad*4 + r;
        const float pp = (float)pos[row];
        float s0, c0, s1, c1;
        __sincosf(pp * eff0, &s0, &c0);
        __sincosf(pp * eff1, &s1, &c1);
        const float v0 = acc[i][0][r] + bv[0];
        const float v1 = acc[i][1][r] + bv[1];
        const float v2 = acc[i][2][r] + bv[2];
        const float v3 = acc[i][3][r] + bv[3];
        const float o0 = v0*c0 - v2*s0;
        const float o1 = v1*c1 - v3*s1;
        const float o2 = v2*c0 + v0*s0;
        const float o3 = v3*c1 + v1*s1;
        const size_t base = (size_t)row*N + n0 + wn + fm;
        if (OUT_BF16){
          unsigned short* C16 = (unsigned short*)Cout;
          C16[base +  0] = f2bf(o0); C16[base + 16] = f2bf(o1);
          C16[base + 32] = f2bf(o2); C16[base + 48] = f2bf(o3);
        } else {
          float* C32 = (float*)Cout;
          C32[base +  0] = o0; C32[base + 16] = o1;
          C32[base + 32] = o2; C32[base + 48] = o3;
        }
      }
    }
  } else {
#pragma unroll
    for (int i = 0; i < MI; ++i){
#pragma unroll
      for (int r = 0; r < 4; ++r){
        const int row = m0 + wm + i*16 + quad*4 + r;
        const size_t base = (size_t)row*N + n0 + wn + fm;
#pragma unroll
        for (int j = 0; j < 4; ++j){
          const float v = acc[i][j][r] + bv[j];
          if (OUT_BF16) ((unsigned short*)Cout)[base + j*16] = f2bf(v);
          else          ((float*)Cout)[base + j*16] = v;
        }
      }
    }
  }
}

// ---------------- QKV GEMM: 64x192 tile, 6 waves, IN-BLOCK SPLIT-K=2 ----------------
// Waves 0-2 compute K=[0,1024), waves 3-5 K=[1024,2048); wave pair (w, w+3) owns the
// same 64x64 output band (wn = (wid%3)*64). Grid 512 = 2 blocks/CU -> 12 waves/CU
// (3/SIMD) at ds_read/MFMA ratio 0.5, same total LDS + staging traffic as round 3.
// BK=32 epochs, depth-2 ping-pong, counted vmcnt, swizzled LDS (conflict-free).
// LDS: 4 regions [half*2+parity] x (A 2048 | B 6144) shorts = 64 KB; reused as the
// f32 combine buffer after the K loop.
__global__ __launch_bounds__(384) void gemm_qkv(const unsigned short* __restrict__ A,
                                                const unsigned short* __restrict__ B,
                                                const float* __restrict__ bias,
                                                unsigned short* __restrict__ C,
                                                const int* __restrict__ pos){
  constexpr int N = 3072, K = 2048;
  __shared__ unsigned short Lds[4*8192];   // 64 KB
  const int tid  = threadIdx.x;
  const int lane = tid & 63;
  const int wid  = tid >> 6;            // 0..5
  const int half = wid / 3;             // K-half
  const int ww   = wid % 3;             // col band index
  const int m0 = blockIdx.y * 64;
  const int n0 = blockIdx.x * 192;
  const int wn = ww * 64;               // 64-aligned -> rope pairing ok
  const int fm = lane & 15;
  const int quad = lane >> 4;
  const int csw8 = (quad ^ ((fm >> 1) & 3)) * 8;

  f32x4 acc[4][4];
#pragma unroll
  for (int i = 0; i < 4; ++i)
#pragma unroll
    for (int j = 0; j < 4; ++j) acc[i][j] = {0.f, 0.f, 0.f, 0.f};

  const int srow = lane >> 2;                               // 0..15
  const int scol = (((lane & 3) ^ ((lane >> 3) & 3)) * 8);  // pre-swizzled source col

  // 16 issues per half-epoch: u<4 -> A row-chunk u; u>=4 -> B row-chunk u-4.
  // wave ww owns u = ww, ww+3, ... (ww=0: 6 slots, ww=1/2: 5 slots).
  const unsigned short* gsrc[6];
  int ldst[6];
#pragma unroll
  for (int i = 0; i < 6; ++i){
    int u = ww + i*3;
    if (u >= 16) u = 0;                 // unused slot guard (ww!=0, i=5)
    const int isA = (u < 4) ? 1 : 0;
    const unsigned short* gp = isA ? (A + (size_t)(m0 + u*16 + srow) * K)
                                   : (B + (size_t)(n0 + (u-4)*16 + srow) * K);
    gsrc[i] = gp + scol + half*1024;
    ldst[i] = half*16384 + (isA ? (u*512) : (2048 + (u-4)*512));
  }

  auto stage = [&](int t, int poff){
    const size_t koff = (size_t)t * 32;
#pragma unroll
    for (int i = 0; i < 5; ++i)
      __builtin_amdgcn_global_load_lds((GPTR)(gsrc[i] + koff), (LPTR)(Lds + ldst[i] + poff), 16, 0, 0);
    if (ww == 0)
      __builtin_amdgcn_global_load_lds((GPTR)(gsrc[5] + koff), (LPTR)(Lds + ldst[5] + poff), 16, 0, 0);
  };

  stage(0, 0);
  stage(1, 8192);

  constexpr int KEP = 32;   // 32-wide epochs over this wave's K-half (1024)
  for (int e = 0; e < KEP; ++e){
    const int poff = (e & 1) * 8192;
    if (e + 1 < KEP){
      if (ww == 0) asm volatile("s_waitcnt vmcnt(6)" ::: "memory");
      else         asm volatile("s_waitcnt vmcnt(5)" ::: "memory");
    } else {
      asm volatile("s_waitcnt vmcnt(0)" ::: "memory");
    }
    asm volatile("s_barrier" ::: "memory");

    const unsigned short* Ab = Lds + half*16384 + poff;
    const unsigned short* Bb = Ab + 2048;
    bf16x8 af[4], bfr[4];
#pragma unroll
    for (int i = 0; i < 4; ++i) af[i]  = *(const bf16x8*)&Ab[(i*16 + fm)*32 + csw8];
#pragma unroll
    for (int j = 0; j < 4; ++j) bfr[j] = *(const bf16x8*)&Bb[(wn + j*16 + fm)*32 + csw8];
#pragma unroll
    for (int i = 0; i < 4; ++i)
#pragma unroll
      for (int j = 0; j < 4; ++j)
        acc[i][j] = __builtin_amdgcn_mfma_f32_16x16x32_bf16(af[i], bfr[j], acc[i][j], 0, 0, 0);

    asm volatile("s_barrier" ::: "memory");
    if (e + 2 < KEP) stage(e+2, poff);   // parity of e+2 == parity of e
  }

  // ---- combine K-halves through LDS (col-major, stride 68 floats: conflict-light) ----
  // band ww: base ww*4352 floats; addr = base + (j*16+fm)*68 + i*16 + quad*4 (f32x4 over r)
  float* Lf = (float*)Lds;
  __syncthreads();                       // staging reads all done (loop's last barrier) + re-use LDS
  if (wid >= 3){
#pragma unroll
    for (int i = 0; i < 4; ++i)
#pragma unroll
      for (int j = 0; j < 4; ++j)
        *(f32x4*)&Lf[ww*4352 + (j*16 + fm)*68 + i*16 + quad*4] = acc[i][j];
  }
  __syncthreads();
  if (wid >= 3) return;

#pragma unroll
  for (int i = 0; i < 4; ++i)
#pragma unroll
    for (int j = 0; j < 4; ++j)
      acc[i][j] += *(const f32x4*)&Lf[ww*4352 + (j*16 + fm)*68 + i*16 + quad*4];

  // ---- epilogue: bias + fused YaRN rope, bf16 store (waves 0-2 only) ----
  float bv[4];
#pragma unroll
  for (int j = 0; j < 4; ++j) bv[j] = bias[n0 + wn + j*16 + fm];

  const bool dorope = (n0 + wn) < 2560;   // Q: 0..2047, K: 2048..2559; V untouched
  if (dorope){
    const float eff0 = yarn_eff((float)fm);
    const float eff1 = yarn_eff((float)(fm + 16));
#pragma unroll
    for (int i = 0; i < 4; ++i){
#pragma unroll
      for (int r = 0; r < 4; ++r){
        const int row = m0 + i*16 + quad*4 + r;
        const float pp = (float)pos[row];
        float s0, c0, s1, c1;
        __sincosf(pp * eff0, &s0, &c0);
        __sincosf(pp * eff1, &s1, &c1);
        const float v0 = acc[i][0][r] + bv[0];
        const float v1 = acc[i][1][r] + bv[1];
        const float v2 = acc[i][2][r] + bv[2];
        const float v3 = acc[i][3][r] + bv[3];
        const float o0 = v0*c0 - v2*s0;
        const float o1 = v1*c1 - v3*s1;
        const float o2 = v2*c0 + v0*s0;
        const float o3 = v3*c1 + v1*s1;
        const size_t base = (size_t)row*N + n0 + wn + fm;
        C[base +  0] = f2bf(o0); C[base + 16] = f2bf(o1);
        C[base + 32] = f2bf(o2); C[base + 48] = f2bf(o3);
      }
    }
  } else {
#pragma unroll
    for (int i = 0; i < 4; ++i){
#pragma unroll
      for (int r = 0; r < 4; ++r){
        const int row = m0 + i*16 + quad*4 + r;
        const size_t base = (size_t)row*N + n0 + wn + fm;
#pragma unroll
        for (int j = 0; j < 4; ++j)
          C[base + j*16] = f2bf(acc[i][j][r] + bv[j]);
      }
    }
  }
}

// ---------------- MFMA flash attention: sliding-window GQA + sink ----------------
__global__ __launch_bounds__(256) void attn_kernel(const unsigned short* __restrict__ qkv,
                                                   const float* __restrict__ sinks,
                                                   unsigned short* __restrict__ ctxb,
                                                   const float* __restrict__ wout,
                                                   unsigned short* __restrict__ wob){
  const int h  = blockIdx.y;
  const int q0 = blockIdx.x * 64;
  const int g  = h >> 2;
  const int tid  = threadIdx.x;
  const int lane = tid & 63;
  const int wid  = tid >> 6;
  const int fm   = lane & 15;
  const int quad = lane >> 4;

  __shared__ unsigned short Ks[2*64*40];   // split-K [ks][key][40]
  __shared__ unsigned short Vt[2*64*34];   // V^T [kk][d][34]
  __shared__ unsigned short Pl[4*2*16*40]; // per-wave P [ks][q16][40]

  const int qrow = q0 + wid*16 + fm;
  bf16x8 aq[2];
#pragma unroll
  for (int ks = 0; ks < 2; ++ks)
    aq[ks] = *(const bf16x8*)(qkv + (size_t)qrow*NQKV + h*HDIM + ks*32 + quad*8);

  f32x4 o[4];
#pragma unroll
  for (int nt = 0; nt < 4; ++nt) o[nt] = {0.f, 0.f, 0.f, 0.f};
  float m_[4], l_[4];
#pragma unroll
  for (int r = 0; r < 4; ++r){ m_[r] = -30000.f; l_[r] = 0.f; }

  const int qbase = q0 + wid*16 + quad*4;
  int cs0 = q0 - 128; if (cs0 < 0) cs0 = 0;
  unsigned short* plw = &Pl[wid*1280];

  for (int cs = cs0; cs <= q0; cs += 64){
    __syncthreads();
#pragma unroll
    for (int it = 0; it < 2; ++it){
      const int e = (tid + it*256) * 8;
      const int key = e >> 6, d0 = e & 63;
      const unsigned short* kp = qkv + (size_t)(cs + key)*NQKV + EMB + g*HDIM + d0;
      *(bf16x8*)&Ks[(d0>>5)*2560 + key*40 + (d0 & 31)] = *(const bf16x8*)kp;
      const bf16x8 vv = *(const bf16x8*)(kp + NKV*HDIM);
      const unsigned short* vs = (const unsigned short*)&vv;
      unsigned short* vt = &Vt[(key>>5)*2176 + (key & 31)];
#pragma unroll
      for (int j = 0; j < 8; ++j) vt[(d0 + j)*34] = vs[j];
    }
    __syncthreads();

    f32x4 sa[4];
#pragma unroll
    for (int nt = 0; nt < 4; ++nt){
      sa[nt] = {0.f, 0.f, 0.f, 0.f};
#pragma unroll
      for (int ks = 0; ks < 2; ++ks){
        const bf16x8 bk = *(const bf16x8*)&Ks[ks*2560 + (nt*16 + fm)*40 + quad*8];
        sa[nt] = __builtin_amdgcn_mfma_f32_16x16x32_bf16(aq[ks], bk, sa[nt], 0, 0, 0);
      }
    }

#pragma unroll
    for (int nt = 0; nt < 4; ++nt){
      const int key = cs + nt*16 + fm;
#pragma unroll
      for (int r = 0; r < 4; ++r){
        const float s = sa[nt][r] * 0.125f;
        const bool ok = (unsigned)(qbase + r - key) < 128u;
        sa[nt][r] = ok ? s : -1e30f;
      }
    }

#pragma unroll
    for (int r = 0; r < 4; ++r){
      float t = fmaxf(fmaxf(sa[0][r], sa[1][r]), fmaxf(sa[2][r], sa[3][r]));
#pragma unroll
      for (int off = 1; off < 16; off <<= 1) t = fmaxf(t, __shfl_xor(t, off, 64));
      const float nm = fmaxf(m_[r], t);
      const float al = __expf(m_[r] - nm);
#pragma unroll
      for (int nt = 0; nt < 4; ++nt) sa[nt][r] = __expf(sa[nt][r] - nm);
      float ts = (sa[0][r] + sa[1][r]) + (sa[2][r] + sa[3][r]);
#pragma unroll
      for (int off = 1; off < 16; off <<= 1) ts += __shfl_xor(ts, off, 64);
      l_[r] = l_[r]*al + ts;
      m_[r] = nm;
#pragma unroll
      for (int nt = 0; nt < 4; ++nt) o[nt][r] *= al;
    }

#pragma unroll
    for (int nt = 0; nt < 4; ++nt)
#pragma unroll
      for (int r = 0; r < 4; ++r)
        plw[(nt>>1)*640 + (quad*4 + r)*40 + (nt&1)*16 + fm] = f2bf(sa[nt][r]);
    __asm__ volatile("s_waitcnt lgkmcnt(0)" ::: "memory");

    bf16x8 pa[2];
#pragma unroll
    for (int ks = 0; ks < 2; ++ks)
      pa[ks] = *(const bf16x8*)&plw[ks*640 + fm*40 + quad*8];
    const unsigned int* vb = (const unsigned int*)Vt;
#pragma unroll
    for (int nt = 0; nt < 4; ++nt){
#pragma unroll
      for (int ks = 0; ks < 2; ++ks){
        const int ui = ks*1088 + (nt*16 + fm)*17 + quad*4;
        union { unsigned int u[4]; bf16x8 v; } bb;
        bb.u[0] = vb[ui+0]; bb.u[1] = vb[ui+1]; bb.u[2] = vb[ui+2]; bb.u[3] = vb[ui+3];
        o[nt] = __builtin_amdgcn_mfma_f32_16x16x32_bf16(pa[ks], bb.v, o[nt], 0, 0, 0);
      }
    }
  }

  const float snk = sinks[h];
#pragma unroll
  for (int r = 0; r < 4; ++r){
    const float nm = fmaxf(m_[r], snk);
    const float e  = __expf(m_[r] - nm);
    const float denom = l_[r]*e + __expf(snk - nm);
    const float sc = e / denom;
    const size_t row = (size_t)(qbase + r)*EMB + h*HDIM;
#pragma unroll
    for (int nt = 0; nt < 4; ++nt)
      ctxb[row + nt*16 + fm] = f2bf(o[nt][r] * sc);
  }

  // ---- fused Wout fp32->bf16 ----
  const int gtid = (blockIdx.y * 32 + blockIdx.x) * 256 + tid;
#pragma unroll
  for (int it = 0; it < 4; ++it){
    const int i4 = gtid + it * (32*32*256);
    const float4 v = ((const float4*)wout)[i4];
    ushort4 ow;
    ow.x = f2bf(v.x); ow.y = f2bf(v.y); ow.z = f2bf(v.z); ow.w = f2bf(v.w);
    ((ushort4*)wob)[i4] = ow;
  }
}

// ---------------- launch ----------------
extern "C" void kernel_launch(void* const* d_in, const int* in_sizes, int n_in,
                              void* d_out, int out_size, void* d_ws, size_t ws_size,
                              hipStream_t stream){
  const float* x     = (const float*)d_in[0];
  const int*   pos   = (const int*)  d_in[1];
  const float* Wqkv  = (const float*)d_in[3];
  const float* bqkv  = (const float*)d_in[4];
  const float* Wout  = (const float*)d_in[5];
  const float* bout  = (const float*)d_in[6];
  const float* sinks = (const float*)d_in[7];

  char* ws = (char*)d_ws;
  unsigned short* xb   = (unsigned short*)(ws);                      //  8,388,608 B
  unsigned short* wqb  = (unsigned short*)(ws + 8388608);            // 12,582,912 B
  unsigned short* wob  = (unsigned short*)(ws + 20971520);           //  8,388,608 B
  unsigned short* qkv  = (unsigned short*)(ws + 29360128);           // 12,582,912 B
  unsigned short* ctxb = (unsigned short*)(ws + 41943040);           //  8,388,608 B

  cvt3_kernel<<<dim3(10240), dim3(256), 0, stream>>>(x, xb, 1048576,
                                                     Wqkv, wqb, 1572864,
                                                     nullptr, nullptr, 0);

  // qkv = rope(x @ Wqkv^T + bqkv)  (2048x3072x2048), 64x192 tile, split-K=2 in-block,
  // 512 blocks (2/CU, 12 waves/CU)
  gemm_qkv<<<dim3(16, 32), dim3(384), 0, stream>>>(xb, wqb, bqkv, qkv, pos);
  // attention -> ctx (bf16) + fused Wout cvt
  attn_kernel<<<dim3(32, 32), dim3(256), 0, stream>>>(qkv, sinks, ctxb, Wout, wob);
  // out = ctx @ Wout^T + bout  (2048x2048x2048), fp32 out, 64x128 tile (2 blk/CU)
  gemm_bt<0,0,64><<<dim3(16, 32), dim3(256), 0, stream>>>(ctxb, wob, bout, d_out, nullptr, 2048, 2048, 2048);
}

// Round 5
// 201.511 us; speedup vs baseline: 1.0138x; 1.0138x over previous
//
#include <hip/hip_runtime.h>
#include <cstdint>

#define S_LEN 2048
#define EMB   2048
#define NHEAD 32
#define NKV   8
#define HDIM  64
#define NQKV  3072   // (H+2G)*D

typedef __attribute__((ext_vector_type(8))) short bf16x8;
typedef __attribute__((ext_vector_type(4))) float f32x4;

#define GPTR const __attribute__((address_space(1))) void*
#define LPTR __attribute__((address_space(3))) void*

__device__ __forceinline__ unsigned short f2bf(float f){
  union { float f; unsigned int u; } v; v.f = f;
  unsigned int r = v.u + 0x7FFFu + ((v.u >> 16) & 1u);
  return (unsigned short)(r >> 16);
}
__device__ __forceinline__ float bf2f(unsigned short u){
  union { unsigned int u; float f; } v; v.u = ((unsigned int)u) << 16;
  return v.f;
}
__device__ __forceinline__ float yarn_eff(float ifr){
  const float freq = __expf(-ifr * (9.210340371976184f / 32.0f));  // 10000^(-2i/64)
  const float wl = 6.283185307179586f / freq;
  float t = fminf(fmaxf((wl - 128.0f) * (1.0f / 3968.0f), 0.f), 1.f);
  return freq * (1.0f - 0.5f * t) * 1.0693147180559945f;           // * conc
}

// ---------------- fp32 -> bf16 conversion (x, Wqkv; Wout is fused into attn) ----------------
__global__ __launch_bounds__(256) void cvt3_kernel(const float* __restrict__ a, unsigned short* __restrict__ da, int na,
                                                   const float* __restrict__ b, unsigned short* __restrict__ db, int nb,
                                                   const float* __restrict__ c, unsigned short* __restrict__ dc, int nc){
  int i = blockIdx.x * 256 + threadIdx.x;
  const float* s; unsigned short* d;
  if (i < na){ s = a; d = da; }
  else if (i < na + nb){ s = b; d = db; i -= na; }
  else if (i < na + nb + nc){ s = c; d = dc; i -= na + nb; }
  else return;
  const float4 v = ((const float4*)s)[i];
  ushort4 o;
  o.x = f2bf(v.x); o.y = f2bf(v.y); o.z = f2bf(v.z); o.w = f2bf(v.w);
  ((ushort4*)d)[i] = o;
}

// LDS granule swizzle (both GEMMs): row r's logical k-quad q (16B granule) stored at
// granule q ^ ((r>>1)&3). global_load_lds writes linearly -> swizzle applied by
// permuting the per-lane GLOBAL source column; un-applied on the ds_read side.
// Verified round 1: SQ_LDS_BANK_CONFLICT = 0.
// NOTE (R4 post-mortem): the 2-barrier epoch loop is structurally capped at ~26% of
// MFMA peak (m233 reproduced); tile/wave/occupancy reshuffles inside this family all
// land 39-47 us. Round-3 config below is the measured best -- do not churn further.

// ---------------- bf16 MFMA GEMM, C = A * B^T + bias, TM x 128 tile (out-proj) ----------------
template<int OUT_BF16, int ROPE, int TM>
__global__ __launch_bounds__(256) void gemm_bt(const unsigned short* __restrict__ A,
                                               const unsigned short* __restrict__ B,
                                               const float* __restrict__ bias,
                                               void* __restrict__ Cout,
                                               const int* __restrict__ pos,
                                               int M, int N, int K){
  constexpr int MI = TM / 32;            // i-frags per wave (128->4, 64->2)
  constexpr int AI = TM / 64;            // A staging issues per wave per sub-tile
  __shared__ unsigned short As[4*TM*32];   // 2 epochs x 2 subs
  __shared__ unsigned short Bs[4*128*32];  // 32 KB
  const int tid  = threadIdx.x;
  const int lane = tid & 63;
  const int wid  = tid >> 6;
  const int m0 = blockIdx.y * TM;
  const int n0 = blockIdx.x * 128;
  const int wm = (wid >> 1) * (TM/2);
  const int wn = (wid & 1) * 64;
  const int fm = lane & 15;
  const int quad = lane >> 4;
  const int csw8 = (quad ^ ((fm >> 1) & 3)) * 8;   // swizzled read granule

  f32x4 acc[MI][4];
#pragma unroll
  for (int i = 0; i < MI; ++i)
#pragma unroll
    for (int j = 0; j < 4; ++j) acc[i][j] = {0.f, 0.f, 0.f, 0.f};

  const int srow = lane >> 2;                                    // 0..15
  const int scol = (((lane & 3) ^ ((lane >> 3) & 3)) * 8);       // swizzled source col
  const unsigned short* Ag = A + (size_t)(m0 + wid*(TM/4) + srow) * K + scol;
  const unsigned short* Bg = B + (size_t)(n0 + wid*32 + srow) * K + scol;
  unsigned short* AsW = &As[(wid*(TM/4))*32];
  unsigned short* BsW = &Bs[(wid*32)*32];

  auto stage_sub = [&](int k0, int slot){
    unsigned short* dA = AsW + slot*(TM*32);
    unsigned short* dB = BsW + slot*(128*32);
#pragma unroll
    for (int t = 0; t < AI; ++t)
      __builtin_amdgcn_global_load_lds((GPTR)(Ag + k0 + (size_t)(t*16)*K), (LPTR)(dA + t*16*32), 16, 0, 0);
    __builtin_amdgcn_global_load_lds((GPTR)(Bg + k0), (LPTR)dB, 16, 0, 0);
    __builtin_amdgcn_global_load_lds((GPTR)(Bg + k0 + (size_t)16*K), (LPTR)(dB + 16*32), 16, 0, 0);
  };

  stage_sub(0, 0);  stage_sub(32, 1);
  stage_sub(64, 2); stage_sub(96, 3);

  const int KEP = K >> 6;   // 64-wide epochs
  for (int e = 0; e < KEP; ++e){
    const int buf = e & 1;
    if (e + 1 < KEP){
      if constexpr (TM == 128) asm volatile("s_waitcnt vmcnt(8)" ::: "memory");
      else                     asm volatile("s_waitcnt vmcnt(6)" ::: "memory");
    } else {
      asm volatile("s_waitcnt vmcnt(0)" ::: "memory");
    }
    asm volatile("s_barrier" ::: "memory");

    bf16x8 af[2][MI], bfr[2][4];
#pragma unroll
    for (int s = 0; s < 2; ++s){
      const unsigned short* Ab = As + (buf*2+s)*(TM*32);
      const unsigned short* Bb = Bs + (buf*2+s)*(128*32);
#pragma unroll
      for (int i = 0; i < MI; ++i) af[s][i]  = *(const bf16x8*)&Ab[(wm + i*16 + fm)*32 + csw8];
#pragma unroll
      for (int j = 0; j < 4; ++j)  bfr[s][j] = *(const bf16x8*)&Bb[(wn + j*16 + fm)*32 + csw8];
    }
#pragma unroll
    for (int s = 0; s < 2; ++s)
#pragma unroll
      for (int i = 0; i < MI; ++i)
#pragma unroll
        for (int j = 0; j < 4; ++j)
          acc[i][j] = __builtin_amdgcn_mfma_f32_16x16x32_bf16(af[s][i], bfr[s][j], acc[i][j], 0, 0, 0);

    asm volatile("s_barrier" ::: "memory");
    if (e + 2 < KEP){
      stage_sub((e+2)*64,      buf*2);
      stage_sub((e+2)*64 + 32, buf*2 + 1);
    }
  }

  float bv[4];
#pragma unroll
  for (int j = 0; j < 4; ++j) bv[j] = bias[n0 + wn + j*16 + fm];

  const bool dorope = ROPE && (n0 + wn) < 2560;
  if (dorope){
    const float eff0 = yarn_eff((float)fm);
    const float eff1 = yarn_eff((float)(fm + 16));
#pragma unroll
    for (int i = 0; i < MI; ++i){
#pragma unroll
      for (int r = 0; r < 4; ++r){
        const int row = m0 + wm + i*16 + quad*4 + r;
        const float pp = (float)pos[row];
        float s0, c0, s1, c1;
        __sincosf(pp * eff0, &s0, &c0);
        __sincosf(pp * eff1, &s1, &c1);
        const float v0 = acc[i][0][r] + bv[0];
        const float v1 = acc[i][1][r] + bv[1];
        const float v2 = acc[i][2][r] + bv[2];
        const float v3 = acc[i][3][r] + bv[3];
        const float o0 = v0*c0 - v2*s0;
        const float o1 = v1*c1 - v3*s1;
        const float o2 = v2*c0 + v0*s0;
        const float o3 = v3*c1 + v1*s1;
        const size_t base = (size_t)row*N + n0 + wn + fm;
        if (OUT_BF16){
          unsigned short* C16 = (unsigned short*)Cout;
          C16[base +  0] = f2bf(o0); C16[base + 16] = f2bf(o1);
          C16[base + 32] = f2bf(o2); C16[base + 48] = f2bf(o3);
        } else {
          float* C32 = (float*)Cout;
          C32[base +  0] = o0; C32[base + 16] = o1;
          C32[base + 32] = o2; C32[base + 48] = o3;
        }
      }
    }
  } else {
#pragma unroll
    for (int i = 0; i < MI; ++i){
#pragma unroll
      for (int r = 0; r < 4; ++r){
        const int row = m0 + wm + i*16 + quad*4 + r;
        const size_t base = (size_t)row*N + n0 + wn + fm;
#pragma unroll
        for (int j = 0; j < 4; ++j){
          const float v = acc[i][j][r] + bv[j];
          if (OUT_BF16) ((unsigned short*)Cout)[base + j*16] = f2bf(v);
          else          ((float*)Cout)[base + j*16] = v;
        }
      }
    }
  }
}

// ---------------- QKV GEMM: 64x192 tile, 3 waves of 64x64, grid 512 = 2 blocks/CU ----------------
// Round-3 configuration (best measured: ~39-40 us). 2-phase structural cap; frozen.
__global__ __launch_bounds__(192) void gemm_qkv(const unsigned short* __restrict__ A,
                                                const unsigned short* __restrict__ B,
                                                const float* __restrict__ bias,
                                                unsigned short* __restrict__ C,
                                                const int* __restrict__ pos){
  constexpr int N = 3072, K = 2048;
  __shared__ unsigned short Lds[2*16384];   // 64 KB
  const int tid  = threadIdx.x;
  const int lane = tid & 63;
  const int wid  = tid >> 6;            // 0..2
  const int m0 = blockIdx.y * 64;
  const int n0 = blockIdx.x * 192;
  const int wn = wid * 64;              // col band (64-aligned -> rope pairing ok)
  const int fm = lane & 15;
  const int quad = lane >> 4;
  const int csw8 = (quad ^ ((fm >> 1) & 3)) * 8;

  f32x4 acc[4][4];
#pragma unroll
  for (int i = 0; i < 4; ++i)
#pragma unroll
    for (int j = 0; j < 4; ++j) acc[i][j] = {0.f, 0.f, 0.f, 0.f};

  const int srow = lane >> 2;                               // 0..15
  const int scol = (((lane & 3) ^ ((lane >> 3) & 3)) * 8);  // pre-swizzled source col

  // 32 issues/epoch: u<8 -> A (sub=u>>2, rc=u&3); u>=8 -> B (v=u-8, sub=v/12, rc=v%12).
  // wave w owns u = w, w+3, ...  (waves 0,1: 11 issues; wave 2: 10).
  const unsigned short* gsrc[11];
  int ldst[11];   // short offsets within one parity
#pragma unroll
  for (int i = 0; i < 11; ++i){
    int u = wid + i*3;
    if (u >= 32) u = 0;                 // wave 2 slot 10: unused (guarded below)
    int sub, rc, isA;
    if (u < 8){ isA = 1; sub = u >> 2; rc = u & 3; }
    else { const int v = u - 8; isA = 0; sub = v / 12; rc = v % 12; }
    const unsigned short* gp = isA ? (A + (size_t)(m0 + rc*16 + srow) * K)
                                   : (B + (size_t)(n0 + rc*16 + srow) * K);
    gsrc[i] = gp + scol + sub*32;
    ldst[i] = isA ? (sub*2048 + rc*512) : (4096 + sub*6144 + rc*512);
  }

  auto stage = [&](int t, int poff){
    const size_t koff = (size_t)t * 64;
#pragma unroll
    for (int i = 0; i < 10; ++i)
      __builtin_amdgcn_global_load_lds((GPTR)(gsrc[i] + koff), (LPTR)(Lds + ldst[i] + poff), 16, 0, 0);
    if (wid < 2)
      __builtin_amdgcn_global_load_lds((GPTR)(gsrc[10] + koff), (LPTR)(Lds + ldst[10] + poff), 16, 0, 0);
  };

  stage(0, 0);
  stage(1, 16384);

  constexpr int KEP = K >> 6;   // 32 epochs
  for (int e = 0; e < KEP; ++e){
    const int poff = (e & 1) * 16384;
    if (e + 1 < KEP){
      if (wid < 2) asm volatile("s_waitcnt vmcnt(11)" ::: "memory");
      else         asm volatile("s_waitcnt vmcnt(10)" ::: "memory");
    } else {
      asm volatile("s_waitcnt vmcnt(0)" ::: "memory");
    }
    asm volatile("s_barrier" ::: "memory");

    bf16x8 af[2][4], bfr[2][4];
#pragma unroll
    for (int s = 0; s < 2; ++s){
      const unsigned short* Ab = Lds + poff + s*2048;
      const unsigned short* Bb = Lds + poff + 4096 + s*6144;
#pragma unroll
      for (int i = 0; i < 4; ++i) af[s][i]  = *(const bf16x8*)&Ab[(i*16 + fm)*32 + csw8];
#pragma unroll
      for (int j = 0; j < 4; ++j) bfr[s][j] = *(const bf16x8*)&Bb[(wn + j*16 + fm)*32 + csw8];
    }
#pragma unroll
    for (int s = 0; s < 2; ++s)
#pragma unroll
      for (int i = 0; i < 4; ++i)
#pragma unroll
        for (int j = 0; j < 4; ++j)
          acc[i][j] = __builtin_amdgcn_mfma_f32_16x16x32_bf16(af[s][i], bfr[s][j], acc[i][j], 0, 0, 0);

    asm volatile("s_barrier" ::: "memory");
    if (e + 2 < KEP) stage(e+2, poff);   // parity of e+2 == parity of e
  }

  // ---- epilogue: bias + fused YaRN rope, bf16 store ----
  float bv[4];
#pragma unroll
  for (int j = 0; j < 4; ++j) bv[j] = bias[n0 + wn + j*16 + fm];

  const bool dorope = (n0 + wn) < 2560;   // Q: 0..2047, K: 2048..2559; V untouched
  if (dorope){
    const float eff0 = yarn_eff((float)fm);
    const float eff1 = yarn_eff((float)(fm + 16));
#pragma unroll
    for (int i = 0; i < 4; ++i){
#pragma unroll
      for (int r = 0; r < 4; ++r){
        const int row = m0 + i*16 + quad*4 + r;
        const float pp = (float)pos[row];
        float s0, c0, s1, c1;
        __sincosf(pp * eff0, &s0, &c0);
        __sincosf(pp * eff1, &s1, &c1);
        const float v0 = acc[i][0][r] + bv[0];
        const float v1 = acc[i][1][r] + bv[1];
        const float v2 = acc[i][2][r] + bv[2];
        const float v3 = acc[i][3][r] + bv[3];
        const float o0 = v0*c0 - v2*s0;
        const float o1 = v1*c1 - v3*s1;
        const float o2 = v2*c0 + v0*s0;
        const float o3 = v3*c1 + v1*s1;
        const size_t base = (size_t)row*N + n0 + wn + fm;
        C[base +  0] = f2bf(o0); C[base + 16] = f2bf(o1);
        C[base + 32] = f2bf(o2); C[base + 48] = f2bf(o3);
      }
    }
  } else {
#pragma unroll
    for (int i = 0; i < 4; ++i){
#pragma unroll
      for (int r = 0; r < 4; ++r){
        const int row = m0 + i*16 + quad*4 + r;
        const size_t base = (size_t)row*N + n0 + wn + fm;
#pragma unroll
        for (int j = 0; j < 4; ++j)
          C[base + j*16] = f2bf(acc[i][j][r] + bv[j]);
      }
    }
  }
}

// ---------------- MFMA flash attention: sliding-window GQA + sink ----------------
// R5: K is NOT LDS-staged (chunks are 8 KB, L1/L2-hot; per-lane QK fragment is one
// contiguous bf16x8 global load). kf loads issue before the Vt-stage barriers, so
// their latency hides under staging. V keeps the LDS transpose (true gather).
__global__ __launch_bounds__(256) void attn_kernel(const unsigned short* __restrict__ qkv,
                                                   const float* __restrict__ sinks,
                                                   unsigned short* __restrict__ ctxb,
                                                   const float* __restrict__ wout,
                                                   unsigned short* __restrict__ wob){
  const int h  = blockIdx.y;
  const int q0 = blockIdx.x * 64;
  const int g  = h >> 2;
  const int tid  = threadIdx.x;
  const int lane = tid & 63;
  const int wid  = tid >> 6;
  const int fm   = lane & 15;
  const int quad = lane >> 4;

  __shared__ unsigned short Vt[2*64*34];   // V^T [kk][d][34]
  __shared__ unsigned short Pl[4*2*16*40]; // per-wave P [ks][q16][40]

  const int qrow = q0 + wid*16 + fm;
  bf16x8 aq[2];
#pragma unroll
  for (int ks = 0; ks < 2; ++ks)
    aq[ks] = *(const bf16x8*)(qkv + (size_t)qrow*NQKV + h*HDIM + ks*32 + quad*8);

  f32x4 o[4];
#pragma unroll
  for (int nt = 0; nt < 4; ++nt) o[nt] = {0.f, 0.f, 0.f, 0.f};
  float m_[4], l_[4];
#pragma unroll
  for (int r = 0; r < 4; ++r){ m_[r] = -30000.f; l_[r] = 0.f; }

  const int qbase = q0 + wid*16 + quad*4;
  int cs0 = q0 - 128; if (cs0 < 0) cs0 = 0;
  unsigned short* plw = &Pl[wid*1280];

  for (int cs = cs0; cs <= q0; cs += 64){
    // direct K fragments for this chunk (global, no LDS) — issue before the barriers
    bf16x8 kf[4][2];
#pragma unroll
    for (int nt = 0; nt < 4; ++nt)
#pragma unroll
      for (int ks = 0; ks < 2; ++ks)
        kf[nt][ks] = *(const bf16x8*)(qkv + (size_t)(cs + nt*16 + fm)*NQKV + EMB + g*HDIM + ks*32 + quad*8);

    __syncthreads();   // protect Vt overwrite vs previous iteration's PV reads
#pragma unroll
    for (int it = 0; it < 2; ++it){
      const int e = (tid + it*256) * 8;
      const int key = e >> 6, d0 = e & 63;
      const bf16x8 vv = *(const bf16x8*)(qkv + (size_t)(cs + key)*NQKV + EMB + NKV*HDIM + g*HDIM + d0);
      const unsigned short* vs = (const unsigned short*)&vv;
      unsigned short* vt = &Vt[(key>>5)*2176 + (key & 31)];
#pragma unroll
      for (int j = 0; j < 8; ++j) vt[(d0 + j)*34] = vs[j];
    }
    __syncthreads();

    f32x4 sa[4];
#pragma unroll
    for (int nt = 0; nt < 4; ++nt){
      sa[nt] = {0.f, 0.f, 0.f, 0.f};
#pragma unroll
      for (int ks = 0; ks < 2; ++ks)
        sa[nt] = __builtin_amdgcn_mfma_f32_16x16x32_bf16(aq[ks], kf[nt][ks], sa[nt], 0, 0, 0);
    }

#pragma unroll
    for (int nt = 0; nt < 4; ++nt){
      const int key = cs + nt*16 + fm;
#pragma unroll
      for (int r = 0; r < 4; ++r){
        const float s = sa[nt][r] * 0.125f;
        const bool ok = (unsigned)(qbase + r - key) < 128u;
        sa[nt][r] = ok ? s : -1e30f;
      }
    }

#pragma unroll
    for (int r = 0; r < 4; ++r){
      float t = fmaxf(fmaxf(sa[0][r], sa[1][r]), fmaxf(sa[2][r], sa[3][r]));
#pragma unroll
      for (int off = 1; off < 16; off <<= 1) t = fmaxf(t, __shfl_xor(t, off, 64));
      const float nm = fmaxf(m_[r], t);
      const float al = __expf(m_[r] - nm);
#pragma unroll
      for (int nt = 0; nt < 4; ++nt) sa[nt][r] = __expf(sa[nt][r] - nm);
      float ts = (sa[0][r] + sa[1][r]) + (sa[2][r] + sa[3][r]);
#pragma unroll
      for (int off = 1; off < 16; off <<= 1) ts += __shfl_xor(ts, off, 64);
      l_[r] = l_[r]*al + ts;
      m_[r] = nm;
#pragma unroll
      for (int nt = 0; nt < 4; ++nt) o[nt][r] *= al;
    }

#pragma unroll
    for (int nt = 0; nt < 4; ++nt)
#pragma unroll
      for (int r = 0; r < 4; ++r)
        plw[(nt>>1)*640 + (quad*4 + r)*40 + (nt&1)*16 + fm] = f2bf(sa[nt][r]);
    __asm__ volatile("s_waitcnt lgkmcnt(0)" ::: "memory");

    bf16x8 pa[2];
#pragma unroll
    for (int ks = 0; ks < 2; ++ks)
      pa[ks] = *(const bf16x8*)&plw[ks*640 + fm*40 + quad*8];
    const unsigned int* vb = (const unsigned int*)Vt;
#pragma unroll
    for (int nt = 0; nt < 4; ++nt){
#pragma unroll
      for (int ks = 0; ks < 2; ++ks){
        const int ui = ks*1088 + (nt*16 + fm)*17 + quad*4;
        union { unsigned int u[4]; bf16x8 v; } bb;
        bb.u[0] = vb[ui+0]; bb.u[1] = vb[ui+1]; bb.u[2] = vb[ui+2]; bb.u[3] = vb[ui+3];
        o[nt] = __builtin_amdgcn_mfma_f32_16x16x32_bf16(pa[ks], bb.v, o[nt], 0, 0, 0);
      }
    }
  }

  const float snk = sinks[h];
#pragma unroll
  for (int r = 0; r < 4; ++r){
    const float nm = fmaxf(m_[r], snk);
    const float e  = __expf(m_[r] - nm);
    const float denom = l_[r]*e + __expf(snk - nm);
    const float sc = e / denom;
    const size_t row = (size_t)(qbase + r)*EMB + h*HDIM;
#pragma unroll
    for (int nt = 0; nt < 4; ++nt)
      ctxb[row + nt*16 + fm] = f2bf(o[nt][r] * sc);
  }

  // ---- fused Wout fp32->bf16 ----
  const int gtid = (blockIdx.y * 32 + blockIdx.x) * 256 + tid;
#pragma unroll
  for (int it = 0; it < 4; ++it){
    const int i4 = gtid + it * (32*32*256);
    const float4 v = ((const float4*)wout)[i4];
    ushort4 ow;
    ow.x = f2bf(v.x); ow.y = f2bf(v.y); ow.z = f2bf(v.z); ow.w = f2bf(v.w);
    ((ushort4*)wob)[i4] = ow;
  }
}

// ---------------- launch ----------------
extern "C" void kernel_launch(void* const* d_in, const int* in_sizes, int n_in,
                              void* d_out, int out_size, void* d_ws, size_t ws_size,
                              hipStream_t stream){
  const float* x     = (const float*)d_in[0];
  const int*   pos   = (const int*)  d_in[1];
  const float* Wqkv  = (const float*)d_in[3];
  const float* bqkv  = (const float*)d_in[4];
  const float* Wout  = (const float*)d_in[5];
  const float* bout  = (const float*)d_in[6];
  const float* sinks = (const float*)d_in[7];

  char* ws = (char*)d_ws;
  unsigned short* xb   = (unsigned short*)(ws);                      //  8,388,608 B
  unsigned short* wqb  = (unsigned short*)(ws + 8388608);            // 12,582,912 B
  unsigned short* wob  = (unsigned short*)(ws + 20971520);           //  8,388,608 B
  unsigned short* qkv  = (unsigned short*)(ws + 29360128);           // 12,582,912 B
  unsigned short* ctxb = (unsigned short*)(ws + 41943040);           //  8,388,608 B

  cvt3_kernel<<<dim3(10240), dim3(256), 0, stream>>>(x, xb, 1048576,
                                                     Wqkv, wqb, 1572864,
                                                     nullptr, nullptr, 0);

  // qkv = rope(x @ Wqkv^T + bqkv)  (2048x3072x2048), 64x192 tile, 3 waves, 512 blocks (2/CU)
  gemm_qkv<<<dim3(16, 32), dim3(192), 0, stream>>>(xb, wqb, bqkv, qkv, pos);
  // attention -> ctx (bf16) + fused Wout cvt
  attn_kernel<<<dim3(32, 32), dim3(256), 0, stream>>>(qkv, sinks, ctxb, Wout, wob);
  // out = ctx @ Wout^T + bout  (2048x2048x2048), fp32 out, 64x128 tile (2 blk/CU)
  gemm_bt<0,0,64><<<dim3(16, 32), dim3(256), 0, stream>>>(ctxb, wob, bout, d_out, nullptr, 2048, 2048, 2048);
}

// Round 7
// 194.538 us; speedup vs baseline: 1.0501x; 1.0358x over previous
//
#include <hip/hip_runtime.h>
#include <cstdint>

#define S_LEN 2048
#define EMB   2048
#define NHEAD 32
#define NKV   8
#define HDIM  64
#define NQKV  3072   // (H+2G)*D

typedef __attribute__((ext_vector_type(8))) short bf16x8;
typedef __attribute__((ext_vector_type(4))) float f32x4;

#define GPTR const __attribute__((address_space(1))) void*
#define LPTR __attribute__((address_space(3))) void*

__device__ __forceinline__ unsigned short f2bf(float f){
  union { float f; unsigned int u; } v; v.f = f;
  unsigned int r = v.u + 0x7FFFu + ((v.u >> 16) & 1u);
  return (unsigned short)(r >> 16);
}
__device__ __forceinline__ float bf2f(unsigned short u){
  union { unsigned int u; float f; } v; v.u = ((unsigned int)u) << 16;
  return v.f;
}
__device__ __forceinline__ float yarn_eff(float ifr){
  const float freq = __expf(-ifr * (9.210340371976184f / 32.0f));  // 10000^(-2i/64)
  const float wl = 6.283185307179586f / freq;
  float t = fminf(fmaxf((wl - 128.0f) * (1.0f / 3968.0f), 0.f), 1.f);
  return freq * (1.0f - 0.5f * t) * 1.0693147180559945f;           // * conc
}

// ---------------- fp32 -> bf16 conversion (x, Wqkv; Wout is fused into attn) ----------------
__global__ __launch_bounds__(256) void cvt3_kernel(const float* __restrict__ a, unsigned short* __restrict__ da, int na,
                                                   const float* __restrict__ b, unsigned short* __restrict__ db, int nb,
                                                   const float* __restrict__ c, unsigned short* __restrict__ dc, int nc){
  int i = blockIdx.x * 256 + threadIdx.x;
  const float* s; unsigned short* d;
  if (i < na){ s = a; d = da; }
  else if (i < na + nb){ s = b; d = db; i -= na; }
  else if (i < na + nb + nc){ s = c; d = dc; i -= na + nb; }
  else return;
  const float4 v = ((const float4*)s)[i];
  ushort4 o;
  o.x = f2bf(v.x); o.y = f2bf(v.y); o.z = f2bf(v.z); o.w = f2bf(v.w);
  ((ushort4*)d)[i] = o;
}

// LDS granule swizzle: row r's logical k-quad q stored at q ^ ((r>>1)&3); applied by
// permuting the GLOBAL source column (global_load_lds writes linearly), un-applied on
// the ds_read side. Verified conflict-free (R1: SQ_LDS_BANK_CONFLICT = 0).
// R6 post-mortem: ds_reads issued BEFORE a barrier race against other waves' staging
// (vmcnt is per-wave). Invariant: reads of tile e must follow a barrier that follows
// ALL waves' vmcnt draining stage(e). The 3-buffer schedule below enforces this while
// keeping stage(e+2) in flight across the barrier (counted vmcnt, 1 barrier/K-tile).

// ---------------- bf16 MFMA GEMM, C = A * B^T + bias, TM x 128 tile (out-proj) ----------------
template<int OUT_BF16, int ROPE, int TM>
__global__ __launch_bounds__(256) void gemm_bt(const unsigned short* __restrict__ A,
                                               const unsigned short* __restrict__ B,
                                               const float* __restrict__ bias,
                                               void* __restrict__ Cout,
                                               const int* __restrict__ pos,
                                               int M, int N, int K){
  constexpr int MI = TM / 32;            // i-frags per wave (128->4, 64->2)
  constexpr int AI = TM / 64;            // A staging issues per wave per sub-tile
  __shared__ unsigned short As[4*TM*32];   // 2 epochs x 2 subs
  __shared__ unsigned short Bs[4*128*32];  // 32 KB
  const int tid  = threadIdx.x;
  const int lane = tid & 63;
  const int wid  = tid >> 6;
  const int m0 = blockIdx.y * TM;
  const int n0 = blockIdx.x * 128;
  const int wm = (wid >> 1) * (TM/2);
  const int wn = (wid & 1) * 64;
  const int fm = lane & 15;
  const int quad = lane >> 4;
  const int csw8 = (quad ^ ((fm >> 1) & 3)) * 8;   // swizzled read granule

  f32x4 acc[MI][4];
#pragma unroll
  for (int i = 0; i < MI; ++i)
#pragma unroll
    for (int j = 0; j < 4; ++j) acc[i][j] = {0.f, 0.f, 0.f, 0.f};

  const int srow = lane >> 2;                                    // 0..15
  const int scol = (((lane & 3) ^ ((lane >> 3) & 3)) * 8);       // swizzled source col
  const unsigned short* Ag = A + (size_t)(m0 + wid*(TM/4) + srow) * K + scol;
  const unsigned short* Bg = B + (size_t)(n0 + wid*32 + srow) * K + scol;
  unsigned short* AsW = &As[(wid*(TM/4))*32];
  unsigned short* BsW = &Bs[(wid*32)*32];

  auto stage_sub = [&](int k0, int slot){
    unsigned short* dA = AsW + slot*(TM*32);
    unsigned short* dB = BsW + slot*(128*32);
#pragma unroll
    for (int t = 0; t < AI; ++t)
      __builtin_amdgcn_global_load_lds((GPTR)(Ag + k0 + (size_t)(t*16)*K), (LPTR)(dA + t*16*32), 16, 0, 0);
    __builtin_amdgcn_global_load_lds((GPTR)(Bg + k0), (LPTR)dB, 16, 0, 0);
    __builtin_amdgcn_global_load_lds((GPTR)(Bg + k0 + (size_t)16*K), (LPTR)(dB + 16*32), 16, 0, 0);
  };

  stage_sub(0, 0);  stage_sub(32, 1);
  stage_sub(64, 2); stage_sub(96, 3);

  const int KEP = K >> 6;   // 64-wide epochs
  for (int e = 0; e < KEP; ++e){
    const int buf = e & 1;
    if (e + 1 < KEP){
      if constexpr (TM == 128) asm volatile("s_waitcnt vmcnt(8)" ::: "memory");
      else                     asm volatile("s_waitcnt vmcnt(6)" ::: "memory");
    } else {
      asm volatile("s_waitcnt vmcnt(0)" ::: "memory");
    }
    asm volatile("s_barrier" ::: "memory");

    bf16x8 af[2][MI], bfr[2][4];
#pragma unroll
    for (int s = 0; s < 2; ++s){
      const unsigned short* Ab = As + (buf*2+s)*(TM*32);
      const unsigned short* Bb = Bs + (buf*2+s)*(128*32);
#pragma unroll
      for (int i = 0; i < MI; ++i) af[s][i]  = *(const bf16x8*)&Ab[(wm + i*16 + fm)*32 + csw8];
#pragma unroll
      for (int j = 0; j < 4; ++j)  bfr[s][j] = *(const bf16x8*)&Bb[(wn + j*16 + fm)*32 + csw8];
    }
#pragma unroll
    for (int s = 0; s < 2; ++s)
#pragma unroll
      for (int i = 0; i < MI; ++i)
#pragma unroll
        for (int j = 0; j < 4; ++j)
          acc[i][j] = __builtin_amdgcn_mfma_f32_16x16x32_bf16(af[s][i], bfr[s][j], acc[i][j], 0, 0, 0);

    asm volatile("s_barrier" ::: "memory");
    if (e + 2 < KEP){
      stage_sub((e+2)*64,      buf*2);
      stage_sub((e+2)*64 + 32, buf*2 + 1);
    }
  }

  float bv[4];
#pragma unroll
  for (int j = 0; j < 4; ++j) bv[j] = bias[n0 + wn + j*16 + fm];

  const bool dorope = ROPE && (n0 + wn) < 2560;
  if (dorope){
    const float eff0 = yarn_eff((float)fm);
    const float eff1 = yarn_eff((float)(fm + 16));
#pragma unroll
    for (int i = 0; i < MI; ++i){
#pragma unroll
      for (int r = 0; r < 4; ++r){
        const int row = m0 + wm + i*16 + quad*4 + r;
        const float pp = (float)pos[row];
        float s0, c0, s1, c1;
        __sincosf(pp * eff0, &s0, &c0);
        __sincosf(pp * eff1, &s1, &c1);
        const float v0 = acc[i][0][r] + bv[0];
        const float v1 = acc[i][1][r] + bv[1];
        const float v2 = acc[i][2][r] + bv[2];
        const float v3 = acc[i][3][r] + bv[3];
        const float o0 = v0*c0 - v2*s0;
        const float o1 = v1*c1 - v3*s1;
        const float o2 = v2*c0 + v0*s0;
        const float o3 = v3*c1 + v1*s1;
        const size_t base = (size_t)row*N + n0 + wn + fm;
        if (OUT_BF16){
          unsigned short* C16 = (unsigned short*)Cout;
          C16[base +  0] = f2bf(o0); C16[base + 16] = f2bf(o1);
          C16[base + 32] = f2bf(o2); C16[base + 48] = f2bf(o3);
        } else {
          float* C32 = (float*)Cout;
          C32[base +  0] = o0; C32[base + 16] = o1;
          C32[base + 32] = o2; C32[base + 48] = o3;
        }
      }
    }
  } else {
#pragma unroll
    for (int i = 0; i < MI; ++i){
#pragma unroll
      for (int r = 0; r < 4; ++r){
        const int row = m0 + wm + i*16 + quad*4 + r;
        const size_t base = (size_t)row*N + n0 + wn + fm;
#pragma unroll
        for (int j = 0; j < 4; ++j){
          const float v = acc[i][j][r] + bv[j];
          if (OUT_BF16) ((unsigned short*)Cout)[base + j*16] = f2bf(v);
          else          ((float*)Cout)[base + j*16] = v;
        }
      }
    }
  }
}

// ---------------- QKV GEMM: 128x192, 6 waves of 64x64, 3-buffer 1-barrier pipeline ----------------
// grid 16x16 = 256 = 1 block/CU. LDS 3 x 40960 B = 120 KB.
// iter e: stage(e+2)->buf[(e+2)%3] (freed by barrier ending e-1);
//         read+MFMA sub0, sub1 of tile e (globally valid from prior barrier);
//         vmcnt(ntot) [drains stage(e+1), leaves stage(e+2) IN FLIGHT]; barrier.
__global__ __launch_bounds__(384) void gemm_qkv(const unsigned short* __restrict__ A,
                                                const unsigned short* __restrict__ B,
                                                const float* __restrict__ bias,
                                                unsigned short* __restrict__ C,
                                                const int* __restrict__ pos){
  constexpr int N = 3072, K = 2048;
  constexpr int PS = 20480;               // shorts per buffer: A 2x4096 | B 2x6144
  __shared__ unsigned short Lds[3*PS];    // 120 KB
  const int tid  = threadIdx.x;
  const int lane = tid & 63;
  const int wid  = tid >> 6;              // 0..5
  const int m0 = blockIdx.y * 128;
  const int n0 = blockIdx.x * 192;
  const int wm = (wid & 1) * 64;          // R2-proven mapping
  const int wn = (wid >> 1) * 64;         // 64-aligned -> rope pairing ok
  const int fm = lane & 15;
  const int quad = lane >> 4;
  const int csw8 = (quad ^ ((fm >> 1) & 3)) * 8;

  f32x4 acc[4][4];
#pragma unroll
  for (int i = 0; i < 4; ++i)
#pragma unroll
    for (int j = 0; j < 4; ++j) acc[i][j] = {0.f, 0.f, 0.f, 0.f};

  const int srow = lane >> 2;                               // 0..15
  const int scol = (((lane & 3) ^ ((lane >> 3) & 3)) * 8);  // pre-swizzled source col

  // 40 issues per K-tile: u = sub*20 + v; v<8 -> A chunk v; else B chunk v-8.
  // wave w owns u = w, w+6, ... (waves 0-3: 7 slots, waves 4-5: 6).
  const unsigned short* gsrc[7];
  int ldst[7];
#pragma unroll
  for (int i = 0; i < 7; ++i){
    int u = wid + i*6;
    if (u >= 40) u = 0;                   // unused slot guard (wid>=4, i=6)
    const int sub = (u >= 20) ? 1 : 0;
    const int v   = u - sub*20;
    const int isA = (v < 8) ? 1 : 0;
    const unsigned short* gp = isA ? (A + (size_t)(m0 + v*16 + srow) * K)
                                   : (B + (size_t)(n0 + (v-8)*16 + srow) * K);
    gsrc[i] = gp + scol + sub*32;
    ldst[i] = isA ? (sub*4096 + v*512) : (8192 + sub*6144 + (v-8)*512);
  }

  auto stage = [&](int t, int boff){
    const size_t koff = (size_t)t * 64;
#pragma unroll
    for (int i = 0; i < 6; ++i)
      __builtin_amdgcn_global_load_lds((GPTR)(gsrc[i] + koff), (LPTR)(Lds + ldst[i] + boff), 16, 0, 0);
    if (wid < 4)
      __builtin_amdgcn_global_load_lds((GPTR)(gsrc[6] + koff), (LPTR)(Lds + ldst[6] + boff), 16, 0, 0);
  };

  // prologue: tiles 0,1; drain stage(0) (outstanding 2*ntot -> ntot); globalize
  stage(0, 0);
  stage(1, PS);
  if (wid < 4) asm volatile("s_waitcnt vmcnt(7)" ::: "memory");
  else         asm volatile("s_waitcnt vmcnt(6)" ::: "memory");
  asm volatile("s_barrier" ::: "memory");

  constexpr int KEP = K >> 6;   // 32 K-tiles
  for (int e = 0; e < KEP; ++e){
    const int boff = (e % 3) * PS;
    if (e + 2 < KEP) stage(e + 2, ((e + 2) % 3) * PS);   // buffer freed by barrier ending e-1

#pragma unroll
    for (int s = 0; s < 2; ++s){
      const unsigned short* Ab = Lds + boff + s*4096;
      const unsigned short* Bb = Lds + boff + 8192 + s*6144;
      bf16x8 af[4], bf[4];
#pragma unroll
      for (int i = 0; i < 4; ++i) af[i] = *(const bf16x8*)&Ab[(wm + ((i&1)*16) + ((i>>1)*32) + fm)*32 + csw8];
#pragma unroll
      for (int j = 0; j < 4; ++j) bf[j] = *(const bf16x8*)&Bb[(wn + j*16 + fm)*32 + csw8];
      __builtin_amdgcn_s_setprio(1);
#pragma unroll
      for (int i = 0; i < 4; ++i)
#pragma unroll
        for (int j = 0; j < 4; ++j)
          acc[i][j] = __builtin_amdgcn_mfma_f32_16x16x32_bf16(af[i], bf[j], acc[i][j], 0, 0, 0);
      __builtin_amdgcn_s_setprio(0);
    }

    if (e + 1 < KEP){
      if (e + 2 < KEP){
        if (wid < 4) asm volatile("s_waitcnt vmcnt(7)" ::: "memory");   // drains stage(e+1); stage(e+2) stays in flight
        else         asm volatile("s_waitcnt vmcnt(6)" ::: "memory");
      } else {
        asm volatile("s_waitcnt vmcnt(0)" ::: "memory");                // drain final tile
      }
      asm volatile("s_barrier" ::: "memory");
    }
  }

  // ---- epilogue: bias + fused YaRN rope, bf16 store (R2-proven mapping) ----
  // NOTE: af index mapping above is i -> row wm + (i&1)*16 + (i>>1)*32, so acc[i] rows
  // are m0 + wm + (i&1)*16 + (i>>1)*32. Keep the same mapping here.
  float bv[4];
#pragma unroll
  for (int j = 0; j < 4; ++j) bv[j] = bias[n0 + wn + j*16 + fm];

  const bool dorope = (n0 + wn) < 2560;   // Q: 0..2047, K: 2048..2559; V untouched
  if (dorope){
    const float eff0 = yarn_eff((float)fm);
    const float eff1 = yarn_eff((float)(fm + 16));
#pragma unroll
    for (int i = 0; i < 4; ++i){
#pragma unroll
      for (int r = 0; r < 4; ++r){
        const int row = m0 + wm + (i&1)*16 + (i>>1)*32 + quad*4 + r;
        const float pp = (float)pos[row];
        float s0, c0, s1, c1;
        __sincosf(pp * eff0, &s0, &c0);
        __sincosf(pp * eff1, &s1, &c1);
        const float v0 = acc[i][0][r] + bv[0];
        const float v1 = acc[i][1][r] + bv[1];
        const float v2 = acc[i][2][r] + bv[2];
        const float v3 = acc[i][3][r] + bv[3];
        const float o0 = v0*c0 - v2*s0;
        const float o1 = v1*c1 - v3*s1;
        const float o2 = v2*c0 + v0*s0;
        const float o3 = v3*c1 + v1*s1;
        const size_t base = (size_t)row*N + n0 + wn + fm;
        C[base +  0] = f2bf(o0); C[base + 16] = f2bf(o1);
        C[base + 32] = f2bf(o2); C[base + 48] = f2bf(o3);
      }
    }
  } else {
#pragma unroll
    for (int i = 0; i < 4; ++i){
#pragma unroll
      for (int r = 0; r < 4; ++r){
        const int row = m0 + wm + (i&1)*16 + (i>>1)*32 + quad*4 + r;
        const size_t base = (size_t)row*N + n0 + wn + fm;
#pragma unroll
        for (int j = 0; j < 4; ++j)
          C[base + j*16] = f2bf(acc[i][j][r] + bv[j]);
      }
    }
  }
}

// ---------------- MFMA flash attention: sliding-window GQA + sink (R3 form) ----------------
__global__ __launch_bounds__(256) void attn_kernel(const unsigned short* __restrict__ qkv,
                                                   const float* __restrict__ sinks,
                                                   unsigned short* __restrict__ ctxb,
                                                   const float* __restrict__ wout,
                                                   unsigned short* __restrict__ wob){
  const int h  = blockIdx.y;
  const int q0 = blockIdx.x * 64;
  const int g  = h >> 2;
  const int tid  = threadIdx.x;
  const int lane = tid & 63;
  const int wid  = tid >> 6;
  const int fm   = lane & 15;
  const int quad = lane >> 4;

  __shared__ unsigned short Ks[2*64*40];   // split-K [ks][key][40]
  __shared__ unsigned short Vt[2*64*34];   // V^T [kk][d][34]
  __shared__ unsigned short Pl[4*2*16*40]; // per-wave P [ks][q16][40]

  const int qrow = q0 + wid*16 + fm;
  bf16x8 aq[2];
#pragma unroll
  for (int ks = 0; ks < 2; ++ks)
    aq[ks] = *(const bf16x8*)(qkv + (size_t)qrow*NQKV + h*HDIM + ks*32 + quad*8);

  f32x4 o[4];
#pragma unroll
  for (int nt = 0; nt < 4; ++nt) o[nt] = {0.f, 0.f, 0.f, 0.f};
  float m_[4], l_[4];
#pragma unroll
  for (int r = 0; r < 4; ++r){ m_[r] = -30000.f; l_[r] = 0.f; }

  const int qbase = q0 + wid*16 + quad*4;
  int cs0 = q0 - 128; if (cs0 < 0) cs0 = 0;
  unsigned short* plw = &Pl[wid*1280];

  for (int cs = cs0; cs <= q0; cs += 64){
    __syncthreads();
#pragma unroll
    for (int it = 0; it < 2; ++it){
      const int e = (tid + it*256) * 8;
      const int key = e >> 6, d0 = e & 63;
      const unsigned short* kp = qkv + (size_t)(cs + key)*NQKV + EMB + g*HDIM + d0;
      *(bf16x8*)&Ks[(d0>>5)*2560 + key*40 + (d0 & 31)] = *(const bf16x8*)kp;
      const bf16x8 vv = *(const bf16x8*)(kp + NKV*HDIM);
      const unsigned short* vs = (const unsigned short*)&vv;
      unsigned short* vt = &Vt[(key>>5)*2176 + (key & 31)];
#pragma unroll
      for (int j = 0; j < 8; ++j) vt[(d0 + j)*34] = vs[j];
    }
    __syncthreads();

    f32x4 sa[4];
#pragma unroll
    for (int nt = 0; nt < 4; ++nt){
      sa[nt] = {0.f, 0.f, 0.f, 0.f};
#pragma unroll
      for (int ks = 0; ks < 2; ++ks){
        const bf16x8 bk = *(const bf16x8*)&Ks[ks*2560 + (nt*16 + fm)*40 + quad*8];
        sa[nt] = __builtin_amdgcn_mfma_f32_16x16x32_bf16(aq[ks], bk, sa[nt], 0, 0, 0);
      }
    }

#pragma unroll
    for (int nt = 0; nt < 4; ++nt){
      const int key = cs + nt*16 + fm;
#pragma unroll
      for (int r = 0; r < 4; ++r){
        const float s = sa[nt][r] * 0.125f;
        const bool ok = (unsigned)(qbase + r - key) < 128u;
        sa[nt][r] = ok ? s : -1e30f;
      }
    }

#pragma unroll
    for (int r = 0; r < 4; ++r){
      float t = fmaxf(fmaxf(sa[0][r], sa[1][r]), fmaxf(sa[2][r], sa[3][r]));
#pragma unroll
      for (int off = 1; off < 16; off <<= 1) t = fmaxf(t, __shfl_xor(t, off, 64));
      const float nm = fmaxf(m_[r], t);
      const float al = __expf(m_[r] - nm);
#pragma unroll
      for (int nt = 0; nt < 4; ++nt) sa[nt][r] = __expf(sa[nt][r] - nm);
      float ts = (sa[0][r] + sa[1][r]) + (sa[2][r] + sa[3][r]);
#pragma unroll
      for (int off = 1; off < 16; off <<= 1) ts += __shfl_xor(ts, off, 64);
      l_[r] = l_[r]*al + ts;
      m_[r] = nm;
#pragma unroll
      for (int nt = 0; nt < 4; ++nt) o[nt][r] *= al;
    }

#pragma unroll
    for (int nt = 0; nt < 4; ++nt)
#pragma unroll
      for (int r = 0; r < 4; ++r)
        plw[(nt>>1)*640 + (quad*4 + r)*40 + (nt&1)*16 + fm] = f2bf(sa[nt][r]);
    __asm__ volatile("s_waitcnt lgkmcnt(0)" ::: "memory");

    bf16x8 pa[2];
#pragma unroll
    for (int ks = 0; ks < 2; ++ks)
      pa[ks] = *(const bf16x8*)&plw[ks*640 + fm*40 + quad*8];
    const unsigned int* vb = (const unsigned int*)Vt;
#pragma unroll
    for (int nt = 0; nt < 4; ++nt){
#pragma unroll
      for (int ks = 0; ks < 2; ++ks){
        const int ui = ks*1088 + (nt*16 + fm)*17 + quad*4;
        union { unsigned int u[4]; bf16x8 v; } bb;
        bb.u[0] = vb[ui+0]; bb.u[1] = vb[ui+1]; bb.u[2] = vb[ui+2]; bb.u[3] = vb[ui+3];
        o[nt] = __builtin_amdgcn_mfma_f32_16x16x32_bf16(pa[ks], bb.v, o[nt], 0, 0, 0);
      }
    }
  }

  const float snk = sinks[h];
#pragma unroll
  for (int r = 0; r < 4; ++r){
    const float nm = fmaxf(m_[r], snk);
    const float e  = __expf(m_[r] - nm);
    const float denom = l_[r]*e + __expf(snk - nm);
    const float sc = e / denom;
    const size_t row = (size_t)(qbase + r)*EMB + h*HDIM;
#pragma unroll
    for (int nt = 0; nt < 4; ++nt)
      ctxb[row + nt*16 + fm] = f2bf(o[nt][r] * sc);
  }

  // ---- fused Wout fp32->bf16 ----
  const int gtid = (blockIdx.y * 32 + blockIdx.x) * 256 + tid;
#pragma unroll
  for (int it = 0; it < 4; ++it){
    const int i4 = gtid + it * (32*32*256);
    const float4 v = ((const float4*)wout)[i4];
    ushort4 ow;
    ow.x = f2bf(v.x); ow.y = f2bf(v.y); ow.z = f2bf(v.z); ow.w = f2bf(v.w);
    ((ushort4*)wob)[i4] = ow;
  }
}

// ---------------- launch ----------------
extern "C" void kernel_launch(void* const* d_in, const int* in_sizes, int n_in,
                              void* d_out, int out_size, void* d_ws, size_t ws_size,
                              hipStream_t stream){
  const float* x     = (const float*)d_in[0];
  const int*   pos   = (const int*)  d_in[1];
  const float* Wqkv  = (const float*)d_in[3];
  const float* bqkv  = (const float*)d_in[4];
  const float* Wout  = (const float*)d_in[5];
  const float* bout  = (const float*)d_in[6];
  const float* sinks = (const float*)d_in[7];

  char* ws = (char*)d_ws;
  unsigned short* xb   = (unsigned short*)(ws);                      //  8,388,608 B
  unsigned short* wqb  = (unsigned short*)(ws + 8388608);            // 12,582,912 B
  unsigned short* wob  = (unsigned short*)(ws + 20971520);           //  8,388,608 B
  unsigned short* qkv  = (unsigned short*)(ws + 29360128);           // 12,582,912 B
  unsigned short* ctxb = (unsigned short*)(ws + 41943040);           //  8,388,608 B

  cvt3_kernel<<<dim3(10240), dim3(256), 0, stream>>>(x, xb, 1048576,
                                                     Wqkv, wqb, 1572864,
                                                     nullptr, nullptr, 0);

  // qkv = rope(x @ Wqkv^T + bqkv)  (2048x3072x2048), 128x192, 3-buffer pipeline, 256 blocks (1/CU)
  gemm_qkv<<<dim3(16, 16), dim3(384), 0, stream>>>(xb, wqb, bqkv, qkv, pos);
  // attention -> ctx (bf16) + fused Wout cvt
  attn_kernel<<<dim3(32, 32), dim3(256), 0, stream>>>(qkv, sinks, ctxb, Wout, wob);
  // out = ctx @ Wout^T + bout  (2048x2048x2048), fp32 out, 64x128 tile (2 blk/CU)
  gemm_bt<0,0,64><<<dim3(16, 32), dim3(256), 0, stream>>>(ctxb, wob, bout, d_out, nullptr, 2048, 2048, 2048);
}